// Round 3
// baseline (156.265 us; speedup 1.0000x reference)
//
#include <hip/hip_runtime.h>
#include <stdint.h>

#define M_TOTAL 32768   // B*T
#define NUMS    512
#define DIM     1024
#define TOPK    33

typedef __bf16 bf16_t;
typedef bf16_t bf16x8 __attribute__((ext_vector_type(8)));
typedef float  f32x4  __attribute__((ext_vector_type(4)));
typedef unsigned short ushort_t;

__device__ __forceinline__ ushort_t f2bf(float f) {
    union { float f; uint32_t u; } x; x.f = f;
    uint32_t r = x.u + 0x7FFFu + ((x.u >> 16) & 1u);
    return (ushort_t)(r >> 16);
}
__device__ __forceinline__ float bf2f(uint32_t u) {
    union { uint32_t u; float f; } x; x.u = u << 16;
    return x.f;
}

// global_load_lds: linear LDS dest (wave-uniform base + lane*16), per-lane global src
#define GLDS16(g, l) __builtin_amdgcn_global_load_lds( \
    (const __attribute__((address_space(1))) void*)(g), \
    (__attribute__((address_space(3))) void*)(l), 16, 0, 0)

// ---------------------------------------------------------------------------
// prep: mem fp32 [512][1024] -> memB bf16 [512][1024] and memT bf16 [1024][512]
// ---------------------------------------------------------------------------
__global__ void prep_kernel(const float* __restrict__ mem,
                            ushort_t* __restrict__ memB,
                            ushort_t* __restrict__ memT) {
    __shared__ float tile[32][33];
    const int bi = blockIdx.x;      // 0..15
    const int bj = blockIdx.y;      // 0..31
    const int t  = threadIdx.x;     // 256
    const int r  = t >> 3;
    const int c4 = (t & 7) * 4;

    const float4 v = *(const float4*)(mem + (size_t)(bi * 32 + r) * DIM + bj * 32 + c4);
    ushort4 b;
    b.x = f2bf(v.x); b.y = f2bf(v.y); b.z = f2bf(v.z); b.w = f2bf(v.w);
    *(ushort4*)(memB + (size_t)(bi * 32 + r) * DIM + bj * 32 + c4) = b;
    tile[r][c4 + 0] = v.x; tile[r][c4 + 1] = v.y;
    tile[r][c4 + 2] = v.z; tile[r][c4 + 3] = v.w;
    __syncthreads();
    ushort4 o;
    o.x = f2bf(tile[c4 + 0][r]); o.y = f2bf(tile[c4 + 1][r]);
    o.z = f2bf(tile[c4 + 2][r]); o.w = f2bf(tile[c4 + 3][r]);
    *(ushort4*)(memT + (size_t)(bj * 32 + r) * NUMS + bi * 32 + c4) = o;
}

// ---------------------------------------------------------------------------
// G1: tile 128x512, K=1024, BK=32, double-buffered 2-phase pipeline.
// 512 threads = 8 waves (2x4), wave tile 64x128, acc[4][8].
// LDS 80KB: A0@0 (8K), A1@8192, B0@16384 (32K), B1@49152.
// A reg-staged 2 tiles ahead (fp32->bf16), B via global_load_lds (src-swizzled).
// Swizzle for 64B rows (4 chunks of 16B): slot = chunk ^ ((row ^ (row>>2)) & 3).
// Epilogue: sigmoid -> att (2 half-passes of 64 rows through B-buffer LDS) + top-33.
// ---------------------------------------------------------------------------
__global__ __launch_bounds__(512, 2)
void g1_kernel(const float* __restrict__ data,
               const ushort_t* __restrict__ memB,
               ushort_t* __restrict__ att,
               float* __restrict__ temporal) {
    __shared__ __align__(16) unsigned char smem[81920];
    const int t    = threadIdx.x;
    const int lane = t & 63;
    const int wid  = t >> 6;        // 0..7
    const int wr   = wid >> 2;      // 0..1 : 64 rows each
    const int wc   = wid & 3;       // 0..3 : 128 cols each
    const int kq   = lane >> 4;     // k-quarter 0..3
    const int m0   = blockIdx.x * 128;

    f32x4 zero = {0.f, 0.f, 0.f, 0.f};
    f32x4 acc[4][8];
#pragma unroll
    for (int m = 0; m < 4; ++m)
#pragma unroll
        for (int n = 0; n < 8; ++n) acc[m][n] = zero;

    // ---- A stage mapping (reg path): thread t -> row ar=t>>2, chunk acch=t&3
    const int ar   = t >> 2;
    const int acch = t & 3;
    const int aslot = (acch ^ ar ^ (ar >> 2)) & 3;
    const int aOff  = ar * 64 + aslot * 16;
    const float* aSrcBase = data + (size_t)(m0 + ar) * DIM + acch * 8;

    // ---- B stage mapping (GLDS): wave wid covers rows wid*64 .. +63, 4 issues x 16 rows
    // LDS[row][slot=l&3] holds global chunk slot ^ ((row ^ row>>2) & 3)
    const int bsrcc = ((lane & 3) ^ (lane >> 2) ^ (lane >> 4)) & 3;
    const ushort_t* bSrc = memB + (size_t)(wid * 64 + (lane >> 2)) * DIM + bsrcc * 8;

    float4 pa, pb, qa, qb;

    // ---- prologue: stage tile0 (B GLDS + A convert), load A1 regs
    {
        unsigned char* bd = smem + 16384 + wid * 4096 + lane * 16;
        GLDS16(bSrc,            bd);
        GLDS16(bSrc + 16 * DIM, bd + 1024);
        GLDS16(bSrc + 32 * DIM, bd + 2048);
        GLDS16(bSrc + 48 * DIM, bd + 3072);
        pa = *(const float4*)(aSrcBase);
        pb = *(const float4*)(aSrcBase + 4);
        bf16x8 cv;
        cv[0] = (bf16_t)pa.x; cv[1] = (bf16_t)pa.y; cv[2] = (bf16_t)pa.z; cv[3] = (bf16_t)pa.w;
        cv[4] = (bf16_t)pb.x; cv[5] = (bf16_t)pb.y; cv[6] = (bf16_t)pb.z; cv[7] = (bf16_t)pb.w;
        *(bf16x8*)(smem + aOff) = cv;
        qa = *(const float4*)(aSrcBase + 32);
        qb = *(const float4*)(aSrcBase + 36);
    }
    __syncthreads();

#define G1_BODY(T_, CVA_, CVB_, LDA_, LDB_, PAR_)                               \
    {                                                                           \
        const int tn = (T_) + 1;                                                \
        if (tn < 32) {                                                          \
            const ushort_t* bs = bSrc + tn * 32;                                \
            unsigned char* bd = smem + 16384 + ((tn & 1) ? 32768 : 0)           \
                              + wid * 4096 + lane * 16;                         \
            GLDS16(bs,            bd);                                          \
            GLDS16(bs + 16 * DIM, bd + 1024);                                   \
            GLDS16(bs + 32 * DIM, bd + 2048);                                   \
            GLDS16(bs + 48 * DIM, bd + 3072);                                   \
            bf16x8 cv;                                                          \
            cv[0] = (bf16_t)CVA_.x; cv[1] = (bf16_t)CVA_.y;                     \
            cv[2] = (bf16_t)CVA_.z; cv[3] = (bf16_t)CVA_.w;                     \
            cv[4] = (bf16_t)CVB_.x; cv[5] = (bf16_t)CVB_.y;                     \
            cv[6] = (bf16_t)CVB_.z; cv[7] = (bf16_t)CVB_.w;                     \
            *(bf16x8*)(smem + ((tn & 1) ? 8192 : 0) + aOff) = cv;               \
        }                                                                       \
        if ((T_) + 2 < 32) {                                                    \
            const float* as = aSrcBase + ((T_) + 2) * 32;                       \
            LDA_ = *(const float4*)as;                                          \
            LDB_ = *(const float4*)(as + 4);                                    \
        }                                                                       \
        {                                                                       \
            const unsigned char* ab = smem + ((PAR_) ? 8192 : 0);               \
            const unsigned char* bb = smem + 16384 + ((PAR_) ? 32768 : 0);      \
            bf16x8 af[4], bfr[8];                                               \
            _Pragma("unroll") for (int m = 0; m < 4; ++m) {                     \
                const int row = wr * 64 + m * 16 + (lane & 15);                 \
                const int sl = (kq ^ row ^ (row >> 2)) & 3;                     \
                af[m] = *(const bf16x8*)(ab + row * 64 + sl * 16);              \
            }                                                                   \
            _Pragma("unroll") for (int n = 0; n < 8; ++n) {                     \
                const int col = wc * 128 + n * 16 + (lane & 15);                \
                const int sl = (kq ^ col ^ (col >> 2)) & 3;                     \
                bfr[n] = *(const bf16x8*)(bb + col * 64 + sl * 16);             \
            }                                                                   \
            _Pragma("unroll") for (int m = 0; m < 4; ++m)                       \
                _Pragma("unroll") for (int n = 0; n < 8; ++n)                   \
                    acc[m][n] = __builtin_amdgcn_mfma_f32_16x16x32_bf16(        \
                        af[m], bfr[n], acc[m][n], 0, 0, 0);                     \
        }                                                                       \
        __syncthreads();                                                        \
    }

    for (int tb = 0; tb < 16; ++tb) {
        G1_BODY(2 * tb,     qa, qb, pa, pb, 0)
        G1_BODY(2 * tb + 1, pa, pb, qa, qb, 1)
    }
#undef G1_BODY

    // ---- epilogue: two half-passes of 64 rows through lAtt = smem+16384 (64KB)
    ushort_t* lAtt = (ushort_t*)(smem + 16384);
#pragma unroll
    for (int h = 0; h < 2; ++h) {
        if (h == 1) __syncthreads();   // protect pass-0 reads before overwrite
        if (wr == h) {
#pragma unroll
            for (int m = 0; m < 4; ++m)
#pragma unroll
                for (int n = 0; n < 8; ++n)
#pragma unroll
                    for (int reg = 0; reg < 4; ++reg) {
                        const int rowl = m * 16 + (lane >> 4) * 4 + reg;  // 0..63
                        const int col  = wc * 128 + n * 16 + (lane & 15);
                        const float x = acc[m][n][reg] * 0.03125f;   // /sqrt(1024)
                        const float s = 1.0f / (1.0f + __expf(-x));
                        lAtt[rowl * 512 + col] = f2bf(s);
                    }
        }
        __syncthreads();
        // copy 64KB -> global att (fully coalesced)
        uint4* gdst = (uint4*)(att + (size_t)(m0 + h * 64) * 512);
        const uint4* lsrc = (const uint4*)lAtt;
#pragma unroll
        for (int i = 0; i < 8; ++i) {
            const int idx = i * 512 + t;
            gdst[idx] = lsrc[idx];
        }
        // top-33 mean via ballot radix-select; 8 rows per wave
        for (int ri = 0; ri < 8; ++ri) {
            const int rowl = wid * 8 + ri;
            const uint4 rv = *(const uint4*)(lAtt + rowl * 512 + lane * 8);
            uint32_t u[8];
            u[0] = rv.x & 0xFFFFu; u[1] = rv.x >> 16;
            u[2] = rv.y & 0xFFFFu; u[3] = rv.y >> 16;
            u[4] = rv.z & 0xFFFFu; u[5] = rv.z >> 16;
            u[6] = rv.w & 0xFFFFu; u[7] = rv.w >> 16;
            uint32_t tc = 0;
#pragma unroll
            for (int b = 15; b >= 0; --b) {
                const uint32_t cand = tc | (1u << b);
                int c = 0;
#pragma unroll
                for (int j = 0; j < 8; ++j)
                    c += __popcll(__ballot(u[j] >= cand));
                if (c >= TOPK) tc = cand;
            }
            float sgt = 0.f; int cgt = 0;
#pragma unroll
            for (int j = 0; j < 8; ++j) {
                if (u[j] > tc) { sgt += bf2f(u[j]); cgt++; }
            }
#pragma unroll
            for (int off = 32; off >= 1; off >>= 1) {
                sgt += __shfl_xor(sgt, off);
                cgt += __shfl_xor(cgt, off);
            }
            if (lane == 0)
                temporal[m0 + h * 64 + rowl] =
                    (sgt + (float)(TOPK - cgt) * bf2f(tc)) * (1.0f / 33.0f);
        }
    }
}

// ---------------------------------------------------------------------------
// G2: aug[32768][1024] fp32 = att bf16 @ memT^T. Tile 128x128, BK=64,
// 256 threads = 4 waves (2x2), wave tile 64x64. Double-buffered 2-phase,
// both operands via global_load_lds (src-swizzled), XCD-aware block swizzle.
// LDS 64KB: A0@0 (16K), A1@16384, B0@32768, B1@49152.
// ---------------------------------------------------------------------------
__global__ __launch_bounds__(256, 2)
void g2_kernel(const ushort_t* __restrict__ att,
               const ushort_t* __restrict__ memT,
               float* __restrict__ aug) {
    __shared__ __align__(16) unsigned char smem[65536];
    const int t    = threadIdx.x;
    const int lane = t & 63;
    const int wid  = t >> 6;      // 0..3
    const int wr   = wid >> 1;
    const int wc   = wid & 1;
    // bijective XCD swizzle: 2048 blocks, 8 XCDs, 256 per XCD
    const int wg = (blockIdx.x & 7) * 256 + (blockIdx.x >> 3);
    const int m0 = (wg >> 3) * 128;
    const int n0 = (wg & 7) * 128;

    f32x4 zero = {0.f, 0.f, 0.f, 0.f};
    f32x4 acc[4][4];
#pragma unroll
    for (int m = 0; m < 4; ++m)
#pragma unroll
        for (int n = 0; n < 4; ++n) acc[m][n] = zero;

    // staging: wave wid covers 32 rows (4 GLDS x 8 rows); 128B k-slice per row
    // LDS[row][slot=l&7] holds global chunk slot ^ (row&7), row&7 == l>>3
    const int srcoff = (((lane & 7) ^ (lane >> 3)) & 7) * 8;
    const ushort_t* aS = att  + (size_t)(m0 + wid * 32 + (lane >> 3)) * 512 + srcoff;
    const ushort_t* bS = memT + (size_t)(n0 + wid * 32 + (lane >> 3)) * 512 + srcoff;

#define G2_STAGE(K0_, PAR_)                                                     \
    {                                                                           \
        unsigned char* da = smem + ((PAR_) ? 16384 : 0) + wid * 4096 + lane * 16; \
        unsigned char* db = da + 32768;                                         \
        const ushort_t* sa = aS + (K0_);                                        \
        const ushort_t* sb = bS + (K0_);                                        \
        GLDS16(sa,            da);        GLDS16(sb,            db);            \
        GLDS16(sa +  8 * 512, da + 1024); GLDS16(sb +  8 * 512, db + 1024);     \
        GLDS16(sa + 16 * 512, da + 2048); GLDS16(sb + 16 * 512, db + 2048);     \
        GLDS16(sa + 24 * 512, da + 3072); GLDS16(sb + 24 * 512, db + 3072);     \
    }

    G2_STAGE(0, 0)
    __syncthreads();

    for (int tt = 0; tt < 8; ++tt) {
        if (tt < 7) {
            if ((tt & 1) == 0) G2_STAGE((tt + 1) * 64, 1)
            else               G2_STAGE((tt + 1) * 64, 0)
        }
        const unsigned char* ab = smem + ((tt & 1) ? 16384 : 0);
        const unsigned char* bb = ab + 32768;
#pragma unroll
        for (int ki = 0; ki < 2; ++ki) {
            const int ch = ki * 4 + (lane >> 4);
            bf16x8 af[4], bfr[4];
#pragma unroll
            for (int m = 0; m < 4; ++m) {
                const int row = wr * 64 + m * 16 + (lane & 15);
                af[m] = *(const bf16x8*)(ab + row * 128 + ((ch ^ (row & 7)) << 4));
            }
#pragma unroll
            for (int n = 0; n < 4; ++n) {
                const int col = wc * 64 + n * 16 + (lane & 15);
                bfr[n] = *(const bf16x8*)(bb + col * 128 + ((ch ^ (col & 7)) << 4));
            }
#pragma unroll
            for (int m = 0; m < 4; ++m)
#pragma unroll
                for (int n = 0; n < 4; ++n)
                    acc[m][n] = __builtin_amdgcn_mfma_f32_16x16x32_bf16(
                        af[m], bfr[n], acc[m][n], 0, 0, 0);
        }
        __syncthreads();
    }
#undef G2_STAGE

#pragma unroll
    for (int m = 0; m < 4; ++m)
#pragma unroll
        for (int n = 0; n < 4; ++n)
#pragma unroll
            for (int reg = 0; reg < 4; ++reg) {
                const int row = m0 + wr * 64 + m * 16 + (lane >> 4) * 4 + reg;
                const int col = n0 + wc * 64 + n * 16 + (lane & 15);
                aug[(size_t)row * DIM + col] = acc[m][n][reg];
            }
}

// ---------------------------------------------------------------------------
extern "C" void kernel_launch(void* const* d_in, const int* in_sizes, int n_in,
                              void* d_out, int out_size, void* d_ws, size_t ws_size,
                              hipStream_t stream) {
    const float* data = (const float*)d_in[0];   // [16,2048,1024]
    const float* mem  = (const float*)d_in[1];   // [512,1024]
    float* temporal = (float*)d_out;             // [32768]
    float* aug      = (float*)d_out + M_TOTAL;   // [32768,1024]

    ushort_t* memB = (ushort_t*)d_ws;                    // 512*1024 bf16 (1MB)
    ushort_t* memT = memB + (size_t)NUMS * DIM;          // 1024*512 bf16 (1MB)
    ushort_t* attw = memT + (size_t)DIM * NUMS;          // 32768*512 bf16 (32MB)

    prep_kernel<<<dim3(16, 32), 256, 0, stream>>>(mem, memB, memT);
    g1_kernel<<<M_TOTAL / 128, 512, 0, stream>>>(data, memB, attw, temporal);
    g2_kernel<<<(M_TOTAL / 128) * (DIM / 128), 256, 0, stream>>>(attw, memT, aug);
}

// Round 4
// 147.174 us; speedup vs baseline: 1.0618x; 1.0618x over previous
//
#include <hip/hip_runtime.h>
#include <stdint.h>

#define M_TOTAL 32768   // B*T
#define NUMS    512
#define DIM     1024
#define TOPK    33

typedef __bf16 bf16_t;
typedef bf16_t bf16x8 __attribute__((ext_vector_type(8)));
typedef float  f32x4  __attribute__((ext_vector_type(4)));
typedef unsigned short ushort_t;

__device__ __forceinline__ ushort_t f2bf(float f) {
    union { float f; uint32_t u; } x; x.f = f;
    uint32_t r = x.u + 0x7FFFu + ((x.u >> 16) & 1u);
    return (ushort_t)(r >> 16);
}
__device__ __forceinline__ float bf2f(uint32_t u) {
    union { uint32_t u; float f; } x; x.u = u << 16;
    return x.f;
}

// global_load_lds: wave-uniform LDS base (HW adds lane*16), per-lane global src
#define GLDS16(g, l) __builtin_amdgcn_global_load_lds( \
    (const __attribute__((address_space(1))) void*)(g), \
    (__attribute__((address_space(3))) void*)(l), 16, 0, 0)

// ---------------------------------------------------------------------------
// prep: mem fp32 [512][1024] -> memB bf16 [512][1024] and memT bf16 [1024][512]
// ---------------------------------------------------------------------------
__global__ void prep_kernel(const float* __restrict__ mem,
                            ushort_t* __restrict__ memB,
                            ushort_t* __restrict__ memT) {
    __shared__ float tile[32][33];
    const int bi = blockIdx.x;      // 0..15
    const int bj = blockIdx.y;      // 0..31
    const int t  = threadIdx.x;     // 256
    const int r  = t >> 3;
    const int c4 = (t & 7) * 4;

    const float4 v = *(const float4*)(mem + (size_t)(bi * 32 + r) * DIM + bj * 32 + c4);
    ushort4 b;
    b.x = f2bf(v.x); b.y = f2bf(v.y); b.z = f2bf(v.z); b.w = f2bf(v.w);
    *(ushort4*)(memB + (size_t)(bi * 32 + r) * DIM + bj * 32 + c4) = b;
    tile[r][c4 + 0] = v.x; tile[r][c4 + 1] = v.y;
    tile[r][c4 + 2] = v.z; tile[r][c4 + 3] = v.w;
    __syncthreads();
    ushort4 o;
    o.x = f2bf(tile[c4 + 0][r]); o.y = f2bf(tile[c4 + 1][r]);
    o.z = f2bf(tile[c4 + 2][r]); o.w = f2bf(tile[c4 + 3][r]);
    *(ushort4*)(memT + (size_t)(bj * 32 + r) * NUMS + bi * 32 + c4) = o;
}

// ---------------------------------------------------------------------------
// G1: tile 128x512, BK=32, 32 K-steps. 8 waves (2x4), wave tile 64x128,
// acc[4][8]. Counted-vmcnt pipeline, ONE raw s_barrier per K-step.
// LDS 80KB: A0@0(8K) A1@8192 B0@16384(32K) B1@49152.
// B via global_load_lds (linear dest, src chunk pre-swizzled);
// A via reg-stage 2 iterations ahead (fp32->bf16) + swizzled ds_write_b128.
// Swizzle (64B rows, 4x16B slots): slot = chunk ^ ((row ^ row>>2) & 3).
// vmcnt ledger (issue order per iter: G(t+1)x2 [ph1], G(t+1)x2, A(t+2)x2 [ph2]):
//   ph1 entry: vmcnt(2)  -> all 4 G(t) done (A(t+1) still in flight)
//   ph2 mid:   vmcnt(6)  -> A(t+1) regs arrived (6 = G(t+1)x4 + A(t+2)x2)
// ---------------------------------------------------------------------------
__global__ __launch_bounds__(512, 2)
void g1_kernel(const float* __restrict__ data,
               const ushort_t* __restrict__ memB,
               ushort_t* __restrict__ att,
               float* __restrict__ temporal) {
    __shared__ __align__(16) unsigned char smem[81920];
    const int t    = threadIdx.x;
    const int lane = t & 63;
    const int wid  = t >> 6;        // 0..7
    const int wr   = wid >> 2;      // 0..1 : 64 rows
    const int wc   = wid & 3;       // 0..3 : 128 cols
    const int kq   = lane >> 4;     // 0..3
    const int m0   = blockIdx.x * 128;

    f32x4 zero = {0.f, 0.f, 0.f, 0.f};
    f32x4 acc[4][8];
#pragma unroll
    for (int m = 0; m < 4; ++m)
#pragma unroll
        for (int n = 0; n < 8; ++n) acc[m][n] = zero;

    // ---- A staging (reg path): thread -> row ar=t>>2 (0..127), chunk acch=t&3
    const int ar    = t >> 2;
    const int acch  = t & 3;
    const int aWOff = ar * 64 + ((acch ^ ((ar ^ (ar >> 2)) & 3)) << 4);
    const float* aSrc = data + (size_t)(m0 + ar) * DIM + acch * 8;

    // ---- B staging (GLDS): wave wid stages rows wid*64..+63, 4 issues x 16 rows
    const int csrc = ((lane & 3) ^ ((lane >> 2) ^ (lane >> 4))) & 3;
    const ushort_t* bSrcL = memB + (size_t)(wid * 64 + (lane >> 2)) * DIM + csrc * 8;
    const int bDstW = 16384 + wid * 4096;    // + i*1024, lane*16 implicit

    // ---- fragment read bases (swz same for all m/n since +16 preserves it)
    const int fswz  = (((lane & 15) ^ ((lane & 15) >> 2)) ^ kq) & 3;
    const int aROff = (wr * 64 + (lane & 15)) * 64 + (fswz << 4);     // + m*1024
    const int bROff = (wc * 128 + (lane & 15)) * 64 + (fswz << 4);    // + n*1024

    float4 pa0, pa1, qa0, qa1;

    // ---- prologue: A0 loads FIRST (oldest), then GLDS B0 x4
    pa0 = *(const float4*)(aSrc);
    pa1 = *(const float4*)(aSrc + 4);
#pragma unroll
    for (int i = 0; i < 4; ++i)
        GLDS16(bSrcL + (size_t)i * 16 * DIM, smem + bDstW + i * 1024);
    asm volatile("s_waitcnt vmcnt(4)" ::: "memory");   // A0 arrived
    {
        bf16x8 cv;
        cv[0] = (bf16_t)pa0.x; cv[1] = (bf16_t)pa0.y; cv[2] = (bf16_t)pa0.z; cv[3] = (bf16_t)pa0.w;
        cv[4] = (bf16_t)pa1.x; cv[5] = (bf16_t)pa1.y; cv[6] = (bf16_t)pa1.z; cv[7] = (bf16_t)pa1.w;
        *(bf16x8*)(smem + aWOff) = cv;
    }
    pa0 = *(const float4*)(aSrc + 32);   // A1
    pa1 = *(const float4*)(aSrc + 36);

#define G1_ITER(T_, CA0, CA1, NA0, NA1, PAR_, STAGE_)                           \
    {                                                                           \
        asm volatile("s_waitcnt vmcnt(2) lgkmcnt(0)" ::: "memory");             \
        __builtin_amdgcn_s_barrier();                                           \
        const unsigned char* ab  = smem + ((PAR_) ? 8192 : 0);                  \
        const unsigned char* bb  = smem + 16384 + ((PAR_) ? 32768 : 0);         \
        const int bufN = (PAR_) ? 0 : 32768;                                    \
        bf16x8 af[4], bf0[4], bf1[4];                                           \
        _Pragma("unroll") for (int m = 0; m < 4; ++m)                           \
            af[m] = *(const bf16x8*)(ab + aROff + m * 1024);                    \
        _Pragma("unroll") for (int n = 0; n < 4; ++n)                           \
            bf0[n] = *(const bf16x8*)(bb + bROff + n * 1024);                   \
        if (STAGE_) {                                                           \
            const ushort_t* bs = bSrcL + ((T_) + 1) * 32;                       \
            GLDS16(bs,            smem + bDstW + bufN);                         \
            GLDS16(bs + 16 * DIM, smem + bDstW + bufN + 1024);                  \
        }                                                                       \
        __builtin_amdgcn_s_setprio(1);                                          \
        _Pragma("unroll") for (int m = 0; m < 4; ++m)                           \
            _Pragma("unroll") for (int n = 0; n < 4; ++n)                       \
                acc[m][n] = __builtin_amdgcn_mfma_f32_16x16x32_bf16(            \
                    af[m], bf0[n], acc[m][n], 0, 0, 0);                         \
        __builtin_amdgcn_s_setprio(0);                                          \
        _Pragma("unroll") for (int n = 0; n < 4; ++n)                           \
            bf1[n] = *(const bf16x8*)(bb + bROff + (n + 4) * 1024);             \
        if (STAGE_) {                                                           \
            const ushort_t* bs = bSrcL + ((T_) + 1) * 32;                       \
            GLDS16(bs + 32 * DIM, smem + bDstW + bufN + 2048);                  \
            GLDS16(bs + 48 * DIM, smem + bDstW + bufN + 3072);                  \
            const int kn = ((T_) + 2 < 32) ? ((T_) + 2) : 31;                   \
            NA0 = *(const float4*)(aSrc + kn * 32);                             \
            NA1 = *(const float4*)(aSrc + kn * 32 + 4);                         \
            asm volatile("s_waitcnt vmcnt(6)" ::: "memory");                    \
            bf16x8 cv;                                                          \
            cv[0] = (bf16_t)CA0.x; cv[1] = (bf16_t)CA0.y;                       \
            cv[2] = (bf16_t)CA0.z; cv[3] = (bf16_t)CA0.w;                       \
            cv[4] = (bf16_t)CA1.x; cv[5] = (bf16_t)CA1.y;                       \
            cv[6] = (bf16_t)CA1.z; cv[7] = (bf16_t)CA1.w;                       \
            *(bf16x8*)(smem + ((PAR_) ? 0 : 8192) + aWOff) = cv;                \
        }                                                                       \
        __builtin_amdgcn_s_setprio(1);                                          \
        _Pragma("unroll") for (int m = 0; m < 4; ++m)                           \
            _Pragma("unroll") for (int n = 0; n < 4; ++n)                       \
                acc[m][n] = __builtin_amdgcn_mfma_f32_16x16x32_bf16(            \
                    af[m], bf1[n], acc[m][n], 0, 0, 0);                         \
        __builtin_amdgcn_s_setprio(0);                                          \
    }

    for (int tb = 0; tb < 15; ++tb) {
        G1_ITER(2 * tb,     pa0, pa1, qa0, qa1, 0, 1)
        G1_ITER(2 * tb + 1, qa0, qa1, pa0, pa1, 1, 1)
    }
    G1_ITER(30, pa0, pa1, qa0, qa1, 0, 1)   // loads dummy A32 (clamped), cvt A31
    G1_ITER(31, qa0, qa1, pa0, pa1, 1, 0)   // compute-only tail
#undef G1_ITER

    __syncthreads();
    // ---- epilogue: two half-passes of 64 rows through lAtt = smem+16384 (64KB)
    ushort_t* lAtt = (ushort_t*)(smem + 16384);
#pragma unroll
    for (int h = 0; h < 2; ++h) {
        if (h == 1) __syncthreads();
        if (wr == h) {
#pragma unroll
            for (int m = 0; m < 4; ++m)
#pragma unroll
                for (int n = 0; n < 8; ++n)
#pragma unroll
                    for (int reg = 0; reg < 4; ++reg) {
                        const int rowl = m * 16 + (lane >> 4) * 4 + reg;  // 0..63
                        const int col  = wc * 128 + n * 16 + (lane & 15);
                        const float x = acc[m][n][reg] * 0.03125f;
                        const float s = 1.0f / (1.0f + __expf(-x));
                        lAtt[rowl * 512 + col] = f2bf(s);
                    }
        }
        __syncthreads();
        uint4* gdst = (uint4*)(att + (size_t)(m0 + h * 64) * 512);
        const uint4* lsrc = (const uint4*)lAtt;
#pragma unroll
        for (int i = 0; i < 8; ++i) {
            const int idx = i * 512 + t;
            gdst[idx] = lsrc[idx];
        }
        for (int ri = 0; ri < 8; ++ri) {
            const int rowl = wid * 8 + ri;
            const uint4 rv = *(const uint4*)(lAtt + rowl * 512 + lane * 8);
            uint32_t u[8];
            u[0] = rv.x & 0xFFFFu; u[1] = rv.x >> 16;
            u[2] = rv.y & 0xFFFFu; u[3] = rv.y >> 16;
            u[4] = rv.z & 0xFFFFu; u[5] = rv.z >> 16;
            u[6] = rv.w & 0xFFFFu; u[7] = rv.w >> 16;
            uint32_t tc = 0;
#pragma unroll
            for (int b = 15; b >= 0; --b) {
                const uint32_t cand = tc | (1u << b);
                int c = 0;
#pragma unroll
                for (int j = 0; j < 8; ++j)
                    c += __popcll(__ballot(u[j] >= cand));
                if (c >= TOPK) tc = cand;
            }
            float sgt = 0.f; int cgt = 0;
#pragma unroll
            for (int j = 0; j < 8; ++j) {
                if (u[j] > tc) { sgt += bf2f(u[j]); cgt++; }
            }
#pragma unroll
            for (int off = 32; off >= 1; off >>= 1) {
                sgt += __shfl_xor(sgt, off);
                cgt += __shfl_xor(cgt, off);
            }
            if (lane == 0)
                temporal[m0 + h * 64 + rowl] =
                    (sgt + (float)(TOPK - cgt) * bf2f(tc)) * (1.0f / 33.0f);
        }
    }
}

// ---------------------------------------------------------------------------
// G2: aug = att bf16 @ memT^T. 128x128, BK=64, 4 waves, double-buffered,
// XCD-swizzled. (unchanged from round 3 — measured ~32us)
// ---------------------------------------------------------------------------
__global__ __launch_bounds__(256, 2)
void g2_kernel(const ushort_t* __restrict__ att,
               const ushort_t* __restrict__ memT,
               float* __restrict__ aug) {
    __shared__ __align__(16) unsigned char smem[65536];
    const int t    = threadIdx.x;
    const int lane = t & 63;
    const int wid  = t >> 6;
    const int wr   = wid >> 1;
    const int wc   = wid & 1;
    const int wg = (blockIdx.x & 7) * 256 + (blockIdx.x >> 3);
    const int m0 = (wg >> 3) * 128;
    const int n0 = (wg & 7) * 128;

    f32x4 zero = {0.f, 0.f, 0.f, 0.f};
    f32x4 acc[4][4];
#pragma unroll
    for (int m = 0; m < 4; ++m)
#pragma unroll
        for (int n = 0; n < 4; ++n) acc[m][n] = zero;

    const int srcoff = (((lane & 7) ^ (lane >> 3)) & 7) * 8;
    const ushort_t* aS = att  + (size_t)(m0 + wid * 32 + (lane >> 3)) * 512 + srcoff;
    const ushort_t* bS = memT + (size_t)(n0 + wid * 32 + (lane >> 3)) * 512 + srcoff;

#define G2_STAGE(K0_, PAR_)                                                     \
    {                                                                           \
        unsigned char* da = smem + ((PAR_) ? 16384 : 0) + wid * 4096 + lane * 16; \
        unsigned char* db = da + 32768;                                         \
        const ushort_t* sa = aS + (K0_);                                        \
        const ushort_t* sb = bS + (K0_);                                        \
        GLDS16(sa,            da);        GLDS16(sb,            db);            \
        GLDS16(sa +  8 * 512, da + 1024); GLDS16(sb +  8 * 512, db + 1024);     \
        GLDS16(sa + 16 * 512, da + 2048); GLDS16(sb + 16 * 512, db + 2048);     \
        GLDS16(sa + 24 * 512, da + 3072); GLDS16(sb + 24 * 512, db + 3072);     \
    }

    G2_STAGE(0, 0)
    __syncthreads();

    for (int tt = 0; tt < 8; ++tt) {
        if (tt < 7) {
            if ((tt & 1) == 0) G2_STAGE((tt + 1) * 64, 1)
            else               G2_STAGE((tt + 1) * 64, 0)
        }
        const unsigned char* ab = smem + ((tt & 1) ? 16384 : 0);
        const unsigned char* bb = ab + 32768;
#pragma unroll
        for (int ki = 0; ki < 2; ++ki) {
            const int ch = ki * 4 + (lane >> 4);
            bf16x8 af[4], bfr[4];
#pragma unroll
            for (int m = 0; m < 4; ++m) {
                const int row = wr * 64 + m * 16 + (lane & 15);
                af[m] = *(const bf16x8*)(ab + row * 128 + ((ch ^ (row & 7)) << 4));
            }
#pragma unroll
            for (int n = 0; n < 4; ++n) {
                const int col = wc * 64 + n * 16 + (lane & 15);
                bfr[n] = *(const bf16x8*)(bb + col * 128 + ((ch ^ (col & 7)) << 4));
            }
#pragma unroll
            for (int m = 0; m < 4; ++m)
#pragma unroll
                for (int n = 0; n < 4; ++n)
                    acc[m][n] = __builtin_amdgcn_mfma_f32_16x16x32_bf16(
                        af[m], bfr[n], acc[m][n], 0, 0, 0);
        }
        __syncthreads();
    }
#undef G2_STAGE

#pragma unroll
    for (int m = 0; m < 4; ++m)
#pragma unroll
        for (int n = 0; n < 4; ++n)
#pragma unroll
            for (int reg = 0; reg < 4; ++reg) {
                const int row = m0 + wr * 64 + m * 16 + (lane >> 4) * 4 + reg;
                const int col = n0 + wc * 64 + n * 16 + (lane & 15);
                aug[(size_t)row * DIM + col] = acc[m][n][reg];
            }
}

// ---------------------------------------------------------------------------
extern "C" void kernel_launch(void* const* d_in, const int* in_sizes, int n_in,
                              void* d_out, int out_size, void* d_ws, size_t ws_size,
                              hipStream_t stream) {
    const float* data = (const float*)d_in[0];   // [16,2048,1024]
    const float* mem  = (const float*)d_in[1];   // [512,1024]
    float* temporal = (float*)d_out;             // [32768]
    float* aug      = (float*)d_out + M_TOTAL;   // [32768,1024]

    ushort_t* memB = (ushort_t*)d_ws;                    // 512*1024 bf16 (1MB)
    ushort_t* memT = memB + (size_t)NUMS * DIM;          // 1024*512 bf16 (1MB)
    ushort_t* attw = memT + (size_t)DIM * NUMS;          // 32768*512 bf16 (32MB)

    prep_kernel<<<dim3(16, 32), 256, 0, stream>>>(mem, memB, memT);
    g1_kernel<<<M_TOTAL / 128, 512, 0, stream>>>(data, memB, attw, temporal);
    g2_kernel<<<(M_TOTAL / 128) * (DIM / 128), 256, 0, stream>>>(attw, memT, aug);
}